// Round 4
// baseline (133.490 us; speedup 1.0000x reference)
//
#include <hip/hip_runtime.h>
#include <cstdint>
#include <cstddef>

typedef __bf16 bf16_t;
typedef __bf16 bf16x4 __attribute__((ext_vector_type(4)));
typedef __bf16 bf16x8 __attribute__((ext_vector_type(8)));
typedef float f32x4 __attribute__((ext_vector_type(4)));

#define M_DIM 4096
#define K_DIM 2048
#define N_DIM 2048
#define KCAT 4096  // fused K: [inputs | Z] and [fwd_w ; rec_w]

// ---- GEMM geometry: 4 waves, per-wave 128x64 output (42.7 FLOP/LDS-byte) ----
#define BM 256
#define BN 128
#define BK 64
#define NT (KCAT / BK)                 // 64 K-tiles
#define A_ELEMS (BM * BK)              // 16384 bf16 (32768 B)
#define B_ELEMS (BN * BK)              // 8192 bf16 (16384 B)
#define PER_BUF (A_ELEMS + B_ELEMS)    // 24576 bf16 = 49152 B
#define B_OFF A_ELEMS
#define LDS_BYTES (3 * PER_BUF * 2)    // 147456 B (3 buffers)

#define MFMA16(a, b, c) \
  __builtin_amdgcn_mfma_f32_16x16x32_bf16((a), (b), (c), 0, 0, 0)

// async global->LDS, 16B/lane (HW: LDS dest = wave-uniform base + lane*16)
__device__ __forceinline__ void gload_lds16(const bf16_t* g, bf16_t* l) {
  __builtin_amdgcn_global_load_lds(
      (const __attribute__((address_space(1))) void*)g,
      (__attribute__((address_space(3))) void*)l, 16, 0, 0);
}

// ---------------------------------------------------------------------------
// Prepass 1: f32 -> bf16, A_cat [M][KCAT] = [inputs | Z], k-contiguous.
// ---------------------------------------------------------------------------
__global__ __launch_bounds__(256) void convert_acat(
    const float* __restrict__ inputs, const float* __restrict__ Z,
    bf16_t* __restrict__ acat) {
  const int g = blockIdx.x * 256 + threadIdx.x;
  const int half = g >> 20;
  const int i = g & 1048575;
  const int m = i >> 8;
  const int kc = (i & 255) * 8;
  const float* src = (half ? Z : inputs) + (size_t)m * K_DIM + kc;
  const float4 v0 = *reinterpret_cast<const float4*>(src);
  const float4 v1 = *reinterpret_cast<const float4*>(src + 4);
  bf16x8 o;
  o[0] = (bf16_t)v0.x; o[1] = (bf16_t)v0.y;
  o[2] = (bf16_t)v0.z; o[3] = (bf16_t)v0.w;
  o[4] = (bf16_t)v1.x; o[5] = (bf16_t)v1.y;
  o[6] = (bf16_t)v1.z; o[7] = (bf16_t)v1.w;
  *reinterpret_cast<bf16x8*>(
      &acat[(size_t)m * KCAT + (size_t)half * K_DIM + kc]) = o;
}

// ---------------------------------------------------------------------------
// Prepass 2: transpose+convert [K][N] f32 weights -> W_cat^T [N][KCAT] bf16.
// ---------------------------------------------------------------------------
__global__ __launch_bounds__(256) void transpose_wcat(
    const float* __restrict__ w1, const float* __restrict__ w2,
    bf16_t* __restrict__ wcat) {
  __shared__ float tile[64][65];
  const int t = threadIdx.x;
  const int half = blockIdx.z;
  const float* __restrict__ src = half ? w2 : w1;
  const int k0 = blockIdx.y * 64;
  const int n0 = blockIdx.x * 64;
#pragma unroll
  for (int p = 0; p < 4; ++p) {
    const int r = p * 16 + (t >> 4);
    const int c = (t & 15) * 4;
    const float4 v = *reinterpret_cast<const float4*>(
        &src[(size_t)(k0 + r) * N_DIM + n0 + c]);
    tile[r][c + 0] = v.x;
    tile[r][c + 1] = v.y;
    tile[r][c + 2] = v.z;
    tile[r][c + 3] = v.w;
  }
  __syncthreads();
#pragma unroll
  for (int p = 0; p < 4; ++p) {
    const int n = p * 16 + (t >> 4);
    const int c = (t & 15) * 4;
    bf16x4 o;
    o[0] = (bf16_t)tile[c + 0][n];
    o[1] = (bf16_t)tile[c + 1][n];
    o[2] = (bf16_t)tile[c + 2][n];
    o[3] = (bf16_t)tile[c + 3][n];
    *reinterpret_cast<bf16x4*>(
        &wcat[(size_t)(n0 + n) * KCAT + (size_t)half * K_DIM + k0 + c]) = o;
  }
}

// ---------------------------------------------------------------------------
// Main GEMM: 4 waves (1/SIMD), per-wave 128x64, BK=64, 3 LDS buffers,
// intra-wave register double-buffer: MFMA(tile t) overlaps ds_read(tile t+1)
// and staging issue (tile t+3). One barrier per K-tile. Counted vmcnt.
// LDS XOR-swizzle (T2): phys 16B-slot = logical ^ (row&7), staged via
// pre-swizzled global source, linear LDS dest (rule 21).
// ---------------------------------------------------------------------------
__global__ __launch_bounds__(256, 1) void lif_gemm_dp(
    const bf16_t* __restrict__ A, const bf16_t* __restrict__ W,
    const float* __restrict__ Iin, const float* __restrict__ Vin,
    const float* __restrict__ Zin,
    float* __restrict__ outZ, float* __restrict__ outI,
    float* __restrict__ outV) {
  extern __shared__ __align__(16) bf16_t lds[];

  const int tid = threadIdx.x;
  const int lane = tid & 63;
  const int wave = tid >> 6;   // 0..3
  const int wm = wave >> 1;    // 0..1 (M half: 128 rows)
  const int wn = wave & 1;     // 0..1 (N half: 64 cols)
  const int l15 = lane & 15;
  const int l4 = lane >> 4;

  // T1: XCD-aware block swizzle (256 blocks, bijective)
  const int bid = blockIdx.x;
  const int swz = (bid & 7) * 32 + (bid >> 3);
  const int m0 = (swz >> 4) * BM;  // 16 m-tiles
  const int n0 = (swz & 15) * BN;  // 16 n-tiles

  // ---- staging addresses (pre-swizzled global source, linear LDS dest) ----
  const int lr = lane >> 3;        // row-in-group 0..7
  const int sg = (lane & 7) ^ lr;  // swizzled logical 16B-slot
  const bf16_t* aSrc[8];
  const bf16_t* bSrc[4];
  int aDst[8], bDst[4];
#pragma unroll
  for (int i = 0; i < 8; ++i) {
    const int r = wave * 64 + i * 8 + lr;  // A rows 0..255
    aSrc[i] = A + (size_t)(m0 + r) * KCAT + sg * 8;
    aDst[i] = r * BK + (lane & 7) * 8;     // = uniform + lane*16B
  }
#pragma unroll
  for (int i = 0; i < 4; ++i) {
    const int r = wave * 32 + i * 8 + lr;  // B rows 0..127
    bSrc[i] = W + (size_t)(n0 + r) * KCAT + sg * 8;
    bDst[i] = B_OFF + r * BK + (lane & 7) * 8;
  }

  // ---- fragment lane-bases (swizzled read), elements within buffer ----
  int aBase[2], bBase[2];
#pragma unroll
  for (int ks = 0; ks < 2; ++ks) {
    const int phys = (l4 + ks * 4) ^ (l15 & 7);
    aBase[ks] = (wm * 128 + l15) * BK + phys * 8;
    bBase[ks] = B_OFF + (wn * 64 + l15) * BK + phys * 8;
  }

  f32x4 acc[8][4];
#pragma unroll
  for (int i = 0; i < 8; ++i)
#pragma unroll
    for (int j = 0; j < 4; ++j)
#pragma unroll
      for (int e = 0; e < 4; ++e) acc[i][j][e] = 0.0f;

  bf16x8 A0[8][2], B0[4][2], A1[8][2], B1[4][2];

  // ---- prologue: stage tiles 0,1,2 into bufs 0,1,2 ----
#pragma unroll
  for (int tt = 0; tt < 3; ++tt) {
    bf16_t* sp = lds + tt * PER_BUF;
#pragma unroll
    for (int i = 0; i < 8; ++i) gload_lds16(aSrc[i] + tt * BK, sp + aDst[i]);
#pragma unroll
    for (int i = 0; i < 4; ++i) gload_lds16(bSrc[i] + tt * BK, sp + bDst[i]);
  }
  asm volatile("s_waitcnt vmcnt(24)" ::: "memory");  // tile 0 landed
  __builtin_amdgcn_sched_barrier(0);
  __builtin_amdgcn_s_barrier();
  __builtin_amdgcn_sched_barrier(0);

  // read tile 0 fragments -> set 0
#pragma unroll
  for (int mi = 0; mi < 8; ++mi) {
    A0[mi][0] = *reinterpret_cast<const bf16x8*>(lds + aBase[0] + mi * 1024);
    A0[mi][1] = *reinterpret_cast<const bf16x8*>(lds + aBase[1] + mi * 1024);
    if (mi < 4) {
      B0[mi][0] = *reinterpret_cast<const bf16x8*>(lds + bBase[0] + mi * 1024);
      B0[mi][1] = *reinterpret_cast<const bf16x8*>(lds + bBase[1] + mi * 1024);
    }
  }

  int bufS = 0;  // buffer to overwrite this iter == buf[t%3]

#define BODY(T, AC, BC, AN, BN_)                                            \
  {                                                                         \
    const int t_ = (T);                                                     \
    asm volatile("s_waitcnt lgkmcnt(0)" ::: "memory");                      \
    __builtin_amdgcn_sched_barrier(0);                                      \
    __builtin_amdgcn_s_barrier();                                           \
    __builtin_amdgcn_sched_barrier(0);                                      \
    bf16_t* sp = lds + bufS * PER_BUF;                                      \
    const int rIdx = (bufS == 2) ? 0 : bufS + 1;                            \
    const bf16_t* rp = lds + rIdx * PER_BUF;                                \
    if (t_ + 3 < NT) {                                                      \
      const int ktN = (t_ + 3) * BK;                                        \
      _Pragma("unroll") for (int i = 0; i < 8; ++i)                         \
          gload_lds16(aSrc[i] + ktN, sp + aDst[i]);                         \
      _Pragma("unroll") for (int i = 0; i < 4; ++i)                         \
          gload_lds16(bSrc[i] + ktN, sp + bDst[i]);                         \
      asm volatile("s_waitcnt vmcnt(24)" ::: "memory");                     \
    } else if (t_ + 2 < NT) {                                               \
      asm volatile("s_waitcnt vmcnt(12)" ::: "memory");                     \
    } else if (t_ + 1 < NT) {                                               \
      asm volatile("s_waitcnt vmcnt(0)" ::: "memory");                      \
    }                                                                       \
    __builtin_amdgcn_sched_barrier(0);                                      \
    const bool doRead = (t_ + 1 < NT);                                      \
    const bf16_t* ra0 = rp + aBase[0];                                      \
    const bf16_t* ra1 = rp + aBase[1];                                      \
    const bf16_t* rb0 = rp + bBase[0];                                      \
    const bf16_t* rb1 = rp + bBase[1];                                      \
    _Pragma("unroll") for (int mi = 0; mi < 8; ++mi) {                      \
      if (doRead) {                                                         \
        AN[mi][0] = *reinterpret_cast<const bf16x8*>(ra0 + mi * 1024);      \
        AN[mi][1] = *reinterpret_cast<const bf16x8*>(ra1 + mi * 1024);      \
        if (mi < 4) {                                                       \
          BN_[mi][0] = *reinterpret_cast<const bf16x8*>(rb0 + mi * 1024);   \
          BN_[mi][1] = *reinterpret_cast<const bf16x8*>(rb1 + mi * 1024);   \
        }                                                                   \
      }                                                                     \
      _Pragma("unroll") for (int ni = 0; ni < 4; ++ni) {                    \
        acc[mi][ni] = MFMA16(AC[mi][0], BC[ni][0], acc[mi][ni]);            \
        acc[mi][ni] = MFMA16(AC[mi][1], BC[ni][1], acc[mi][ni]);            \
      }                                                                     \
    }                                                                       \
    bufS = (bufS == 2) ? 0 : bufS + 1;                                      \
  }

  for (int t = 0; t < NT; t += 2) {
    BODY(t, A0, B0, A1, B1);
    BODY(t + 1, A1, B1, A0, B0);
  }
#undef BODY

  // ---- fused LIF epilogue (layout verified rounds 1-3) ----
  const float alpha = 0.90483741803595957f;  // exp(-0.1)
  const float beta = 0.81873075307798182f;   // exp(-0.2)
#pragma unroll
  for (int mi = 0; mi < 8; ++mi) {
#pragma unroll
    for (int j = 0; j < 4; ++j) {
      const int r = m0 + wm * 128 + mi * 16 + l4 * 4 + j;
#pragma unroll
      for (int ni = 0; ni < 4; ++ni) {
        const int c = n0 + wn * 64 + ni * 16 + l15;
        const size_t idx = (size_t)r * N_DIM + c;
        const float zin = Zin[idx];
        const float nI = alpha * Iin[idx] + acc[mi][ni][j];
        const float nV = (beta * Vin[idx] + nI) * (1.0f - zin);
        outI[idx] = nI;
        outV[idx] = nV;
        outZ[idx] = (nV > 1.0f) ? 1.0f : 0.0f;
      }
    }
  }
}

extern "C" void kernel_launch(void* const* d_in, const int* in_sizes, int n_in,
                              void* d_out, int out_size, void* d_ws,
                              size_t ws_size, hipStream_t stream) {
  const float* inputs = (const float*)d_in[0];
  const float* I = (const float*)d_in[1];
  const float* V = (const float*)d_in[2];
  const float* Z = (const float*)d_in[3];
  const float* fwd_w = (const float*)d_in[4];
  const float* rec_w = (const float*)d_in[5];

  float* outZ = (float*)d_out;
  float* outI = outZ + (size_t)M_DIM * N_DIM;
  float* outV = outI + (size_t)M_DIM * N_DIM;

  const size_t ACAT_BYTES = (size_t)M_DIM * KCAT * sizeof(bf16_t);  // 32 MiB
  bf16_t* acat = (bf16_t*)d_ws;
  bf16_t* wcat = (bf16_t*)((char*)d_ws + ACAT_BYTES);

  hipLaunchKernelGGL(convert_acat, dim3(8192), dim3(256), 0, stream, inputs, Z,
                     acat);
  hipLaunchKernelGGL(transpose_wcat, dim3(N_DIM / 64, K_DIM / 64, 2), dim3(256),
                     0, stream, fwd_w, rec_w, wcat);

  (void)hipFuncSetAttribute(reinterpret_cast<const void*>(lif_gemm_dp),
                            hipFuncAttributeMaxDynamicSharedMemorySize,
                            LDS_BYTES);
  hipLaunchKernelGGL(lif_gemm_dp, dim3((M_DIM / BM) * (N_DIM / BN)), dim3(256),
                     LDS_BYTES, stream, acat, wcat, I, V, Z, outZ, outI, outV);
}